// Round 15
// baseline (72.511 us; speedup 1.0000x reference)
//
#include <hip/hip_runtime.h>

#define NB      65536
#define NUM_T   200
#define SUB     2        // SUB=8/4/2 all measured absmax == 0.0078125 (bf16
                         // comparison floor); threshold 0.0372
#define SS      16       // steps per stage
#define CH      12       // float4 chunks per row per stage (SS*3/4)
#define RSTRIDE 13       // padded row stride in float4 (odd -> bank-conflict-free)
#define NST     12       // full stages (12*16 = 192 steps)
#define TCH     6        // tail chunks (8 steps)

// one RK4 substep on rescaled state (u = beta*S, I); 22 VALU ops
#define SUBSTEP()                                   \
    do {                                            \
        const float bSI1 = u * I;                   \
        const float u2 = fmaf(-cbA, bSI1, u);       \
        const float J1 = fmaf(-cgA, I, I);          \
        const float I2 = fmaf(h2, bSI1, J1);        \
        const float bSI2 = u2 * I2;                 \
        const float u3 = fmaf(-cbA, bSI2, u);       \
        const float J2 = fmaf(-cgA, I2, I);         \
        const float I3 = fmaf(h2, bSI2, J2);        \
        float wb = fmaf(2.0f, bSI2, bSI1);          \
        float wI = fmaf(2.0f, I2, I);               \
        const float bSI3 = u3 * I3;                 \
        const float u4 = fmaf(-cbB, bSI3, u);       \
        const float J3 = fmaf(-cgB, I3, I);         \
        const float I4 = fmaf(h, bSI3, J3);         \
        wb = fmaf(2.0f, bSI3, wb);                  \
        wI = fmaf(2.0f, I3, wI);                    \
        const float bSI4 = u4 * I4;                 \
        wb += bSI4;                                 \
        wI += I4;                                   \
        u = fmaf(-cbF, wb, u);                      \
        const float tt = fmaf(-cgF, wI, I);         \
        I = fmaf(h6, wb, tt);                       \
    } while (0)

// advance one output step (i>0), per-step dt from the fp32 linspace chain
#define STEP(iexpr)                                                     \
    do {                                                                \
        const float tcur = step * (float)(iexpr);                       \
        const float dt   = tcur - tprev;                                \
        tprev = tcur;                                                   \
        const float h  = dt * (1.0f / SUB);                             \
        const float h2 = 0.5f * h;                                      \
        const float h6 = h * (1.0f / 6.0f);                             \
        const float cbA = h2 * beta,  cbB = h * beta,  cbF = h6 * beta; \
        const float cgA = h2 * gamma, cgB = h * gamma, cgF = h6 * gamma;\
        for (int s = 0; s < SUB; ++s) SUBSTEP();                        \
    } while (0)

// compute NQ*4 steps starting at BASE, write 3 chunks per group into row
#define EMIT(BUFI, BASE, NQ)                                            \
    do {                                                                \
        float4* rowp = &lds4[BUFI][tid * RSTRIDE];                      \
        _Pragma("unroll")                                               \
        for (int q4 = 0; q4 < (NQ); ++q4) {                             \
            float c[12];                                                \
            _Pragma("unroll")                                           \
            for (int j = 0; j < 4; ++j) {                               \
                const int i = (BASE) + q4 * 4 + j;                      \
                if (i > 0) STEP(i);                                     \
                const float Sout = bpos ? (u * rbeta) : S0;             \
                c[j * 3 + 0] = Sout;                                    \
                c[j * 3 + 1] = I;                                       \
                c[j * 3 + 2] = 1.0f - Sout - I;                         \
            }                                                           \
            _Pragma("unroll")                                           \
            for (int cc = 0; cc < 3; ++cc)                              \
                rowp[q4 * 3 + cc] = make_float4(c[cc * 4], c[cc * 4 + 1],\
                                                c[cc * 4 + 2], c[cc * 4 + 3]); \
        }                                                               \
    } while (0)

#define LGKM0() asm volatile("s_waitcnt lgkmcnt(0)" ::: "memory")

__global__ __launch_bounds__(256, 1) void sir_rk4_pipe_kernel(
    const float4* __restrict__ params, float* __restrict__ out)
{
    // double-buffered: 2 x 256 rows x 13 float4 = 106496 B (1 block/CU)
    __shared__ float4 lds4[2][256 * RSTRIDE];

    const int tid  = threadIdx.x;
    const int lane = tid & 63;
    const int w    = tid >> 6;
    const int blk  = blockIdx.x;

    const float4 p = params[blk * 256 + tid];
    const float beta  = p.x;
    const float gamma = p.y;
    const float S0    = p.z;

    float u = beta * S0;                // rescaled state u = beta*S
    float I = p.w;

    const bool  bpos  = (beta > 0.0f);
    const float rbeta = bpos ? (1.0f / beta) : 0.0f;

    const float step = 100.0f / 199.0f; // fp32 linspace step
    float tprev = 0.0f;

    const float4* ldsw0 = &lds4[0][(w * 64) * RSTRIDE];
    const float4* ldsw1 = &lds4[1][(w * 64) * RSTRIDE];
    float4* out4 = reinterpret_cast<float4*>(out)
                 + (size_t)(blk * 256 + w * 64) * 150;  // 150 float4 per row

    // ---- prologue: stage 0 into buf0 ----
    EMIT(0, 0, SS / 4);

    // ---- steady: drain stage s while computing stage s+1 ----
    #pragma unroll 1
    for (int s = 0; s < NST - 1; ++s) {         // s = 0..10
        LGKM0();                                 // stage-s ds_writes visible
        const float4* ldsbuf = (s & 1) ? ldsw1 : ldsw0;
        float4 dv[CH];
        #pragma unroll
        for (int k2 = 0; k2 < CH; ++k2) {        // batch all reads
            const int id = k2 * 64 + lane;
            const int r  = id / CH;
            const int j  = id - r * CH;
            dv[k2] = ldsbuf[r * RSTRIDE + j];
        }
        EMIT((s + 1) & 1, (s + 1) * SS, SS / 4); // next stage's compute
        #pragma unroll
        for (int k2 = 0; k2 < CH; ++k2) {        // stores drain under next stage
            const int id = k2 * 64 + lane;
            const int r  = id / CH;
            const int j  = id - r * CH;
            out4[r * 150 + s * CH + j] = dv[k2];
        }
    }

    // ---- s = 11: drain stage 11, compute tail (8 steps) into buf0 ----
    {
        LGKM0();
        float4 dv[CH];
        #pragma unroll
        for (int k2 = 0; k2 < CH; ++k2) {
            const int id = k2 * 64 + lane;
            const int r  = id / CH;
            const int j  = id - r * CH;
            dv[k2] = ldsw1[r * RSTRIDE + j];     // stage 11 lives in buf1
        }
        EMIT(0, NST * SS, 2);                    // steps 192..199 -> buf0
        #pragma unroll
        for (int k2 = 0; k2 < CH; ++k2) {
            const int id = k2 * 64 + lane;
            const int r  = id / CH;
            const int j  = id - r * CH;
            out4[r * 150 + (NST - 1) * CH + j] = dv[k2];
        }
    }

    // ---- tail drain: 6 chunks/row from buf0 ----
    {
        LGKM0();
        float4 dv[TCH];
        #pragma unroll
        for (int k2 = 0; k2 < TCH; ++k2) {
            const int id = k2 * 64 + lane;
            const int r  = id / TCH;
            const int j  = id - r * TCH;
            dv[k2] = ldsw0[r * RSTRIDE + j];
        }
        #pragma unroll
        for (int k2 = 0; k2 < TCH; ++k2) {
            const int id = k2 * 64 + lane;
            const int r  = id / TCH;
            const int j  = id - r * TCH;
            out4[r * 150 + NST * CH + j] = dv[k2];
        }
    }
}

extern "C" void kernel_launch(void* const* d_in, const int* in_sizes, int n_in,
                              void* d_out, int out_size, void* d_ws, size_t ws_size,
                              hipStream_t stream) {
    (void)in_sizes; (void)n_in; (void)out_size; (void)d_ws; (void)ws_size;
    const float4* params = (const float4*)d_in[0];
    float* out = (float*)d_out;
    sir_rk4_pipe_kernel<<<NB / 256, 256, 0, stream>>>(params, out);
}

// Round 16
// 41.069 us; speedup vs baseline: 1.7656x; 1.7656x over previous
//
#include <hip/hip_runtime.h>

#define NB 65536
#define NUM_T 200
#define SUB 2            // SUB=8/4/2 all measured absmax == 0.0078125 (bf16
                         // comparison floor); threshold 0.0372

// one RK4 substep on rescaled state (u = beta*S, I); 22 VALU ops
#define SUBSTEP()                                   \
    do {                                            \
        const float bSI1 = u * I;                   \
        const float u2 = fmaf(-cbA, bSI1, u);       \
        const float J1 = fmaf(-cgA, I, I);          \
        const float I2 = fmaf(h2, bSI1, J1);        \
        const float bSI2 = u2 * I2;                 \
        const float u3 = fmaf(-cbA, bSI2, u);       \
        const float J2 = fmaf(-cgA, I2, I);         \
        const float I3 = fmaf(h2, bSI2, J2);        \
        float wb = fmaf(2.0f, bSI2, bSI1);          \
        float wI = fmaf(2.0f, I2, I);               \
        const float bSI3 = u3 * I3;                 \
        const float u4 = fmaf(-cbB, bSI3, u);       \
        const float J3 = fmaf(-cgB, I3, I);         \
        const float I4 = fmaf(h, bSI3, J3);         \
        wb = fmaf(2.0f, bSI3, wb);                  \
        wI = fmaf(2.0f, I3, wI);                    \
        const float bSI4 = u4 * I4;                 \
        wb += bSI4;                                 \
        wI += I4;                                   \
        u = fmaf(-cbF, wb, u);                      \
        const float tt = fmaf(-cgF, wI, I);         \
        I = fmaf(h6, wb, tt);                       \
    } while (0)

// advance one output step (i>0), per-step dt from the fp32 linspace chain
#define STEP(iexpr)                                                     \
    do {                                                                \
        const float tcur = step * (float)(iexpr);                       \
        const float dt   = tcur - tprev;                                \
        tprev = tcur;                                                   \
        const float h  = dt * (1.0f / SUB);                             \
        const float h2 = 0.5f * h;                                      \
        const float h6 = h * (1.0f / 6.0f);                             \
        const float cbA = h2 * beta,  cbB = h * beta,  cbF = h6 * beta; \
        const float cgA = h2 * gamma, cgB = h * gamma, cgF = h6 * gamma;\
        for (int s = 0; s < SUB; ++s) SUBSTEP();                        \
    } while (0)

// emit one 4-step group (12 floats) into this thread's LDS row, swizzled
#define EMIT_GROUP(Q4, IBASE)                                           \
    do {                                                                \
        float c[12];                                                    \
        _Pragma("unroll")                                               \
        for (int j = 0; j < 4; ++j) {                                   \
            const int i = (IBASE) + j;                                  \
            if (i > 0) STEP(i);                                         \
            const float Sout = bpos ? (u * rbeta) : S0;                 \
            c[j * 3 + 0] = Sout;                                        \
            c[j * 3 + 1] = I;                                           \
            c[j * 3 + 2] = 1.0f - Sout - I;                             \
        }                                                               \
        _Pragma("unroll")                                               \
        for (int cc = 0; cc < 3; ++cc) {                                \
            const int phys = ((Q4) * 3 + cc) ^ sw;                      \
            ldsrow4[phys] = make_float4(c[cc * 4], c[cc * 4 + 1],       \
                                        c[cc * 4 + 2], c[cc * 4 + 3]);  \
        }                                                               \
    } while (0)

__global__ __launch_bounds__(256, 1) void sir_rk4_dense_kernel(
    const float4* __restrict__ params, float* __restrict__ out)
{
    // 256 rows x 24 float4 chunks = 98304 B; wave w owns rows [w*64, w*64+64)
    __shared__ float4 lds4[256 * 24];

    const int tid  = threadIdx.x;
    const int lane = tid & 63;
    const int w    = tid >> 6;
    const int blk  = blockIdx.x;
    const int sw   = lane & 7;          // XOR bank swizzle key

    const float4 p = params[blk * 256 + tid];
    const float beta  = p.x;
    const float gamma = p.y;
    const float S0    = p.z;

    float u = beta * S0;                // rescaled state u = beta*S
    float I = p.w;

    const bool  bpos  = (beta > 0.0f);
    const float rbeta = bpos ? (1.0f / beta) : 0.0f;

    const float step = 100.0f / 199.0f; // fp32 linspace step
    float tprev = 0.0f;

    float4* ldsrow4 = lds4 + tid * 24;            // this thread's row
    const float4* ldsw4 = lds4 + (w * 64) * 24;   // wave slice base
    float4* out4 = reinterpret_cast<float4*>(out)
                 + (size_t)(blk * 256 + w * 64) * 150;  // 150 float4 per row

    // ---- 6 stages x 32 steps ----
    #pragma unroll 1
    for (int stage = 0; stage < 6; ++stage) {
        #pragma unroll 1
        for (int q4 = 0; q4 < 8; ++q4) {
            EMIT_GROUP(q4, stage * 32 + q4 * 4);
        }
        // wave-synchronous: all lanes' ds_writes visible before cross-lane reads
        asm volatile("s_waitcnt lgkmcnt(0)" ::: "memory");
        // dense drain, BATCHED: issue all 24 ds_reads back-to-back (one
        // latency instead of 24 serial ones), then 24 contiguous-run stores.
        // Stores have no waiters -> they drain under the next stage's compute.
        float4 dv[24];
        #pragma unroll
        for (int k = 0; k < 24; ++k) {
            const int id = k * 64 + lane;
            const int r  = id / 24;             // row within wave slice
            const int j  = id - r * 24;         // chunk within stage
            const int ph = j ^ (r & 7);
            dv[k] = ldsw4[r * 24 + ph];
        }
        #pragma unroll
        for (int k = 0; k < 24; ++k) {
            const int id = k * 64 + lane;
            const int r  = id / 24;
            const int j  = id - r * 24;
            out4[r * 150 + stage * 24 + j] = dv[k];
        }
    }

    // ---- tail stage: 8 steps (192..199) = 6 chunks/row ----
    {
        #pragma unroll 1
        for (int q4 = 0; q4 < 2; ++q4) {
            EMIT_GROUP(q4, 192 + q4 * 4);
        }
        asm volatile("s_waitcnt lgkmcnt(0)" ::: "memory");
        float4 dv[6];
        #pragma unroll
        for (int k = 0; k < 6; ++k) {
            const int id = k * 64 + lane;
            const int r  = id / 6;
            const int j  = id - r * 6;
            const int ph = j ^ (r & 7);
            dv[k] = ldsw4[r * 24 + ph];
        }
        #pragma unroll
        for (int k = 0; k < 6; ++k) {
            const int id = k * 64 + lane;
            const int r  = id / 6;
            const int j  = id - r * 6;
            out4[r * 150 + 144 + j] = dv[k];
        }
    }
}

extern "C" void kernel_launch(void* const* d_in, const int* in_sizes, int n_in,
                              void* d_out, int out_size, void* d_ws, size_t ws_size,
                              hipStream_t stream) {
    (void)in_sizes; (void)n_in; (void)out_size; (void)d_ws; (void)ws_size;
    const float4* params = (const float4*)d_in[0];
    float* out = (float*)d_out;
    sir_rk4_dense_kernel<<<NB / 256, 256, 0, stream>>>(params, out);
}